// Round 7
// baseline (131.121 us; speedup 1.0000x reference)
//
#include <hip/hip_runtime.h>
#include <hip/hip_bf16.h>
#include <stdint.h>

// x: [16,128,56,56] f32, w: [256,128,3,3] f32, bias: [256] f32
// out: [16,256,56,56] f32
// Implicit GEMM: M=Cout=256, N=pixels=50176, K = (kh*3+kw, c) = 1152
// Round 14: A-reuse doubling. R7/R8/R13 all hit the SAME 7.2 us per
// M128xN64xK1152 unit per CU regardless of occupancy/buffering -> theory:
// bound by A-panel L2 traffic (590 KB wt re-read per 64 pixels = 463 MB/kernel,
// ~1.3 TB/s effective per XCD). This round: M256xN128 blocks (8 waves = 4 M x
// 2 N, each wave the proven M64xN64 acc4x4 + ROLLED K-loop -> no spill),
// grid 400 = 16 images x 25 tiles (tile 24 is N64; its wn=1 waves compute
// discarded values, stores skipped). A bytes per FLOP HALVED; the 2 N-halves
// read identical A addresses (L1 dedup). LDS 2 x 34 KB phase buffers ->
// 2 blocks/CU, all 400 resident, no generation tail.

typedef __attribute__((ext_vector_type(8))) short short8;
typedef __attribute__((ext_vector_type(4))) float floatx4;

__device__ static inline void gload_lds16(const void* g, void* l) {
  typedef const __attribute__((address_space(1))) unsigned int* gp_t;
  typedef __attribute__((address_space(3))) unsigned int* lp_t;
  __builtin_amdgcn_global_load_lds((gp_t)(uintptr_t)g, (lp_t)(uint32_t)(uintptr_t)l,
                                   16, 0, 0);
}

// ---------- fused pre-pass: NCHW f32 -> padded NHWC bf16 (halo zeroed)
//   + weight f32 -> bf16 in MFMA-frag order wt2[g=m/16][kq][ch][ks][q][r][e]
//   byte strides: r=16, q=256, ks=1024, ch=2048, kq=4096, g=36864 ----------
__global__ __launch_bounds__(256)
void pre_kernel(const float* __restrict__ x, const float* __restrict__ wsrc,
                __hip_bfloat16* __restrict__ xp, __hip_bfloat16* __restrict__ wt) {
  const int b = blockIdx.x;
  if (b < 16 * 58) {
    const int n = b / 58, hp = b % 58;
    __hip_bfloat16* dst = xp + (size_t)(n * 58 + hp) * 58 * 128;
    if (hp == 0 || hp == 57) {
      const uint4 z = {0, 0, 0, 0};
      uint4* p = (uint4*)dst;
      for (int i = threadIdx.x; i < 928; i += 256) p[i] = z;
      return;
    }
    const int h = hp - 1;
    __shared__ float tile[128][57];
    const float* src = x + (size_t)n * (128 * 3136) + h * 56;
    for (int i = threadIdx.x; i < 128 * 14; i += 256) {
      const int c = i / 14, q = i - c * 14;
      const float4 v = ((const float4*)(src + (size_t)c * 3136))[q];
      tile[c][4 * q + 0] = v.x;
      tile[c][4 * q + 1] = v.y;
      tile[c][4 * q + 2] = v.z;
      tile[c][4 * q + 3] = v.w;
    }
    __syncthreads();
    if (threadIdx.x < 32) {
      const uint4 z = {0, 0, 0, 0};
      const int col = (threadIdx.x >> 4) * 57;
      ((uint4*)(dst + (size_t)col * 128))[threadIdx.x & 15] = z;
    }
    __hip_bfloat16* di = dst + 128;
    for (int i = threadIdx.x; i < 56 * 16; i += 256) {
      const int w = i >> 4, c8 = (i & 15) * 8;
      union { uint4 u; __hip_bfloat16 hh[8]; } pk;
#pragma unroll
      for (int j = 0; j < 8; ++j) pk.hh[j] = __float2bfloat16(tile[c8 + j][w]);
      *(uint4*)(di + (size_t)w * 128 + c8) = pk.u;
    }
  } else {
    const int base = (b - 928) * 256 + threadIdx.x;
    for (int t = base; t < 256 * 9 * 128; t += 36 * 256) {
      const int e = t & 7;
      const int rr = (t >> 3) & 15;
      const int q = (t >> 7) & 3;
      const int ks = (t >> 9) & 1;
      const int ch = (t >> 10) & 1;
      const int t11 = t >> 11;
      const int kq = t11 % 9;
      const int g = t11 / 9;
      const int cout = g * 16 + rr;
      const int c = ch * 64 + ks * 32 + q * 8 + e;
      wt[t] = __float2bfloat16(wsrc[(size_t)(cout * 128 + c) * 9 + kq]);
    }
  }
}

// stage one kh-phase (136 rows = 2176 x 16B chunks) into LDS buffer BUF.
// 512 threads: 4 full rounds + 128-chunk tail (waves 0,1). Local row r holds
// padded row P0 + PH*58 + r; chunk c at slot c ^ (r&7) (involution pair with
// the read side; verified R1-R13).
#define STAGE(PH, BUF)                                                        \
  {                                                                           \
    const char* _src = pbase + (PH) * (58 * 256);                             \
    _Pragma("unroll") for (int _i = 0; _i < 4; ++_i) {                        \
      const int _j = _i * 512 + tid;                                          \
      const int _row = _j >> 4;                                               \
      const int _slot = _j & 15;                                              \
      gload_lds16(_src + _row * 256 + ((_slot ^ (_row & 7)) << 4),            \
                  (BUF) + _i * 8192 + wave * 1024);                           \
    }                                                                         \
    if (wave < 2) {                                                           \
      const int _j = 2048 + wave * 64 + lane;                                 \
      const int _row = _j >> 4;                                               \
      const int _slot = _j & 15;                                              \
      gload_lds16(_src + _row * 256 + ((_slot ^ (_row & 7)) << 4),            \
                  (BUF) + 32768 + wave * 1024);                               \
    }                                                                         \
  }

// one kh-phase of compute: 12 K32-steps reading BUF only. ROLLED loop (the
// R13 spill fix): steady-state arch regs ~47 < 64.
#define COMPUTE(P, BUF)                                                       \
  _Pragma("clang loop unroll(disable)") for (int _t = 0; _t < 12; ++_t) {     \
    const int _kw = _t >> 2;                                                  \
    const int _ksl = _t & 3;                                                  \
    const int _ofs = (P) * 3 * 4096 + _kw * 4096 + _ksl * 1024;               \
    _Pragma("unroll") for (int _mt = 0; _mt < 4; ++_mt)                       \
        areg[_mt] = *(const short8*)(pAw + _mt * 36864 + _ofs);               \
    _Pragma("unroll") for (int _nt = 0; _nt < 4; ++_nt) {                     \
      const int _rowL = rbase[_nt] + _kw;                                     \
      const int _pos = (_ksl * 4 + quad) ^ (_rowL & 7);                       \
      bfr[_nt] = *(const short8*)((BUF) + _rowL * 256 + (_pos << 4));         \
    }                                                                         \
    _Pragma("unroll") for (int _mt = 0; _mt < 4; ++_mt)                       \
        _Pragma("unroll") for (int _nt = 0; _nt < 4; ++_nt)                   \
            acc[_mt][_nt] = __builtin_amdgcn_mfma_f32_16x16x32_bf16(          \
                areg[_mt], bfr[_nt], acc[_mt][_nt], 0, 0, 0);                 \
  }

// ---------- main implicit-GEMM MFMA kernel ----------
// 512 thr = 8 waves (wm = wave&3 M-group, wn = wave>>2 N-half), each wave
// M64 x N64 (acc 4x4). Tile M256 x N128, grid 400 = 16 img x 25 tiles
// (t==24 is an N64 tail tile: wn=1 computes discarded values, no stores).
// LDS: two kh-phase buffers, 136 rows x 256B = 34816 B each -> 2 blocks/CU.
__global__ __launch_bounds__(512, 4)
void conv_gemm_kernel(const __hip_bfloat16* __restrict__ xp,
                      const __hip_bfloat16* __restrict__ wt,
                      const float* __restrict__ bias,
                      float* __restrict__ out) {
  __shared__ __align__(16) char smem[2][34816];

  const int tid = threadIdx.x;
  const int lane = tid & 63;
  const int wave = tid >> 6;
  const int wm = wave & 3;
  const int wn = wave >> 2;
  const int col = lane & 15;
  const int quad = lane >> 4;

  // XCD-contiguous tiles: 400 = 8 XCD x 50 (bijective: 400 % 8 == 0)
  const int id = blockIdx.x;
  const int g = (id & 7) * 50 + (id >> 3);
  const int img = g / 25;
  const int t = g - img * 25;
  const int n0 = img * 3136 + t * 128;     // tail tile t==24 has 64 px
  const bool tail = (t == 24);
  const int pmax = img * 3136 + 3135;      // last pixel of this image

  // patch base: padded-pixel index of pixel n0 at tap (0,0)
  const int rem0 = n0 - img * 3136;
  const int hh0 = rem0 / 56;
  const int ww0 = rem0 - hh0 * 56;
  const int P0 = (img * 58 + hh0) * 58 + ww0;
  const char* pbase = (const char*)xp + (size_t)P0 * 256;

  STAGE(0, smem[0]);  // phase-0 patch in flight

  // ---- A-frag base: wt + (wm*4)*36864 + lane*16; mt stride 36864 ----
  // Identical for wn=0/1 -> L1 dedups the duplicate reads.
  const char* pAw = (const char*)wt + (size_t)(wm * 4) * 36864 + lane * 16;

  // ---- per-lane patch row bases (tap (0,0)); clamped for tail wn=1 ----
  int rbase[4];
#pragma unroll
  for (int nt = 0; nt < 4; ++nt) {
    int pix = n0 + wn * 64 + nt * 16 + col;
    if (pix > pmax) pix = pmax;            // tail-tile wn=1: discarded anyway
    const int re = pix - img * 3136;
    const int ph = re / 56;
    const int pw = re - ph * 56;
    rbase[nt] = (ph - hh0) * 58 + (pw - ww0);
  }

  floatx4 acc[4][4];
#pragma unroll
  for (int a = 0; a < 4; ++a)
#pragma unroll
    for (int c = 0; c < 4; ++c) acc[a][c] = (floatx4)0.f;

  short8 areg[4], bfr[4];

  __syncthreads();      // phase-0 patch ready (barrier drains vmcnt)
  STAGE(1, smem[1]);    // async: phase-1 staged during phase-0 compute
  COMPUTE(0, smem[0]);
  __syncthreads();      // phase-1 ready; all waves done reading buf0
  STAGE(2, smem[0]);    // async: phase-2 staged during phase-1 compute
  COMPUTE(1, smem[1]);
  __syncthreads();      // phase-2 ready
  COMPUTE(2, smem[0]);

  // ---- epilogue: bias + store (C/D: row m=quad*4+rr, col n=lane&15) ----
  if (!(tail && wn)) {
    const int rb = quad * 4;
#pragma unroll
    for (int nt = 0; nt < 4; ++nt) {
      const int pix = n0 + wn * 64 + nt * 16 + col;
      const int rem = pix - img * 3136;
      float* op = out + (size_t)img * (256 * 3136) + rem;
#pragma unroll
      for (int mt = 0; mt < 4; ++mt) {
        const int mb = wm * 64 + mt * 16 + rb;
#pragma unroll
        for (int rr = 0; rr < 4; ++rr) {
          op[(size_t)(mb + rr) * 3136] = acc[mt][nt][rr] + bias[mb + rr];
        }
      }
    }
  }
}

// ---------- fallback: direct fp32 conv (only if ws too small) ----------
__global__ __launch_bounds__(256)
void direct_conv_kernel(const float* __restrict__ x, const float* __restrict__ wgt,
                        const float* __restrict__ bias, float* __restrict__ out) {
  const long t = (long)blockIdx.x * 256 + threadIdx.x;
  if (t >= 16L * 256 * 3136) return;
  const int w = t % 56;
  const int h = (t / 56) % 56;
  const int o = (t / 3136) % 256;
  const int n = t / (256L * 3136);
  float s = bias[o];
  for (int c = 0; c < 128; ++c)
    for (int kh = 0; kh < 3; ++kh) {
      const int hh = h + kh - 1;
      if (hh < 0 || hh >= 56) continue;
      for (int kw = 0; kw < 3; ++kw) {
        const int ww = w + kw - 1;
        if (ww < 0 || ww >= 56) continue;
        s += x[((size_t)(n * 128 + c) * 56 + hh) * 56 + ww] *
             wgt[((size_t)(o * 128 + c) * 3 + kh) * 3 + kw];
      }
    }
  out[t] = s;
}

extern "C" void kernel_launch(void* const* d_in, const int* in_sizes, int n_in,
                              void* d_out, int out_size, void* d_ws, size_t ws_size,
                              hipStream_t stream) {
  const float* x = (const float*)d_in[0];
  const float* w = (const float*)d_in[1];
  const float* b = (const float*)d_in[2];
  float* out = (float*)d_out;

  const size_t xp_bytes = (size_t)16 * 58 * 58 * 128 * 2;  // 13,778,944
  const size_t wt_bytes = (size_t)256 * 9 * 128 * 2;       //    589,824
  // Staging bounds: worst tile (img15,t=24) P0=53640; phase-2 staging reaches
  // row P0+116+135 = 53891 -> byte 13,796,352, overrunning xp by 17,408 B into
  // wt (still inside d_ws; values never used by compute). Safe.

  if (ws_size >= xp_bytes + wt_bytes) {
    __hip_bfloat16* xp = (__hip_bfloat16*)d_ws;
    __hip_bfloat16* wt = (__hip_bfloat16*)((char*)d_ws + xp_bytes);
    hipLaunchKernelGGL(pre_kernel, dim3(16 * 58 + 36), dim3(256), 0, stream,
                       x, w, xp, wt);
    hipLaunchKernelGGL(conv_gemm_kernel, dim3(400), dim3(512), 0, stream,
                       xp, wt, b, out);
  } else {
    const long total = 16L * 256 * 3136;
    hipLaunchKernelGGL(direct_conv_kernel, dim3((unsigned)((total + 255) / 256)),
                       dim3(256), 0, stream, x, w, b, out);
  }
}

// Round 8
// 122.184 us; speedup vs baseline: 1.0731x; 1.0731x over previous
//
#include <hip/hip_runtime.h>
#include <hip/hip_bf16.h>
#include <stdint.h>

// x: [16,128,56,56] f32, w: [256,128,3,3] f32, bias: [256] f32
// out: [16,256,56,56] f32
// Implicit GEMM: M=Cout=256, N=pixels=50176, K = (kh*3+kw, c) = 1152
// Round 15: asm-forced A-pipeline. R7/R8/R13/R14 all sit at 13-15.5 us per
// M256xN64xK1152 unit per CU regardless of source-level pipeline depth ->
// theory: hipcc sinks "prefetch" loads back to just-before-use + per-step
// drain waits (documented compiler behavior). This round the A-loads are
// volatile inline-asm global_load_dwordx4 (compiler cannot reorder/re-wait
// them), true distance-2 ping-pong (aregP/Q), counted s_waitcnt vmcnt(4)
// + sched_barrier(0) before each MFMA cluster (never vmcnt(0) in-loop).
// Register cost ~134 -> __launch_bounds__(256,3) (cap 170, comfortable:
// R10/R12 lesson). Grid 784 at 3/CU: 16-block tail priced in.

typedef __attribute__((ext_vector_type(8))) short short8;
typedef __attribute__((ext_vector_type(4))) float floatx4;

__device__ static inline void gload_lds16(const void* g, void* l) {
  typedef const __attribute__((address_space(1))) unsigned int* gp_t;
  typedef __attribute__((address_space(3))) unsigned int* lp_t;
  __builtin_amdgcn_global_load_lds((gp_t)(uintptr_t)g, (lp_t)(uint32_t)(uintptr_t)l,
                                   16, 0, 0);
}

// ---------- fused pre-pass: NCHW f32 -> padded NHWC bf16 (halo zeroed)
//   + weight f32 -> bf16 in MFMA-frag order wt2[g=m/16][kq][ch][ks][q][r][e]
//   byte strides: r=16, q=256, ks=1024, ch=2048, kq=4096, g=36864 ----------
__global__ __launch_bounds__(256)
void pre_kernel(const float* __restrict__ x, const float* __restrict__ wsrc,
                __hip_bfloat16* __restrict__ xp, __hip_bfloat16* __restrict__ wt) {
  const int b = blockIdx.x;
  if (b < 16 * 58) {
    const int n = b / 58, hp = b % 58;
    __hip_bfloat16* dst = xp + (size_t)(n * 58 + hp) * 58 * 128;
    if (hp == 0 || hp == 57) {
      const uint4 z = {0, 0, 0, 0};
      uint4* p = (uint4*)dst;
      for (int i = threadIdx.x; i < 928; i += 256) p[i] = z;
      return;
    }
    const int h = hp - 1;
    __shared__ float tile[128][57];
    const float* src = x + (size_t)n * (128 * 3136) + h * 56;
    for (int i = threadIdx.x; i < 128 * 14; i += 256) {
      const int c = i / 14, q = i - c * 14;
      const float4 v = ((const float4*)(src + (size_t)c * 3136))[q];
      tile[c][4 * q + 0] = v.x;
      tile[c][4 * q + 1] = v.y;
      tile[c][4 * q + 2] = v.z;
      tile[c][4 * q + 3] = v.w;
    }
    __syncthreads();
    if (threadIdx.x < 32) {
      const uint4 z = {0, 0, 0, 0};
      const int col = (threadIdx.x >> 4) * 57;
      ((uint4*)(dst + (size_t)col * 128))[threadIdx.x & 15] = z;
    }
    __hip_bfloat16* di = dst + 128;
    for (int i = threadIdx.x; i < 56 * 16; i += 256) {
      const int w = i >> 4, c8 = (i & 15) * 8;
      union { uint4 u; __hip_bfloat16 hh[8]; } pk;
#pragma unroll
      for (int j = 0; j < 8; ++j) pk.hh[j] = __float2bfloat16(tile[c8 + j][w]);
      *(uint4*)(di + (size_t)w * 128 + c8) = pk.u;
    }
  } else {
    const int base = (b - 928) * 256 + threadIdx.x;
    for (int t = base; t < 256 * 9 * 128; t += 36 * 256) {
      const int e = t & 7;
      const int rr = (t >> 3) & 15;
      const int q = (t >> 7) & 3;
      const int ks = (t >> 9) & 1;
      const int ch = (t >> 10) & 1;
      const int t11 = t >> 11;
      const int kq = t11 % 9;
      const int g = t11 / 9;
      const int cout = g * 16 + rr;
      const int c = ch * 64 + ks * 32 + q * 8 + e;
      wt[t] = __float2bfloat16(wsrc[(size_t)(cout * 128 + c) * 9 + kq]);
    }
  }
}

// stage one kh-phase (68 rows = 1088 x 16B chunks) into LDS buffer BUF.
// Local row r holds padded row P0 + PH*58 + r; chunk c stored at slot
// c ^ (r&7) (involution pair with the read side; verified R1-R13).
#define STAGE(PH, BUF)                                                        \
  {                                                                           \
    const char* _src = pbase + (PH) * (58 * 256);                             \
    _Pragma("unroll") for (int _i = 0; _i < 4; ++_i) {                        \
      const int _j = _i * 256 + tid;                                          \
      const int _row = _j >> 4;                                               \
      const int _slot = _j & 15;                                              \
      gload_lds16(_src + _row * 256 + ((_slot ^ (_row & 7)) << 4),            \
                  (BUF) + _i * 4096 + wave * 1024);                           \
    }                                                                         \
    if (wave == 0) {                                                          \
      const int _j = 1024 + lane;                                             \
      const int _row = _j >> 4;                                               \
      const int _slot = _j & 15;                                              \
      gload_lds16(_src + _row * 256 + ((_slot ^ (_row & 7)) << 4),            \
                  (BUF) + 16384);                                             \
    }                                                                         \
  }

// asm A-load: 16B per lane, 32-bit voffset off SGPR base (wt).
#define ALOAD(DST, VOFF)                                                      \
  asm volatile("global_load_dwordx4 %0, %1, %2"                               \
               : "=v"(DST) : "v"(VOFF), "s"(wtb64) : "memory")

// one K32 half-step: s = 12*P + T, consumes register set SET (parity of T),
// issues A(s+2) back into SET (freed by the MFMAs just issued).
// LASTWAIT: final step of the whole march -> drain (vmcnt(0)).
// SKIP: s+2 > 35 -> no issue (avoid OOB reads past wt).
#define HALF_STEP(SET, T, BUF, LASTWAIT, SKIP)                                \
  {                                                                           \
    const int _t = (T);                                                       \
    const int _kw = _t >> 2;                                                  \
    const int _ksl = _t & 3;                                                  \
    _Pragma("unroll") for (int _nt = 0; _nt < 4; ++_nt) {                     \
      const int _rowL = rbase[_nt] + _kw;                                     \
      const int _pos = (_ksl * 4 + quad) ^ (_rowL & 7);                       \
      bfr[_nt] = *(const short8*)((BUF) + _rowL * 256 + (_pos << 4));         \
    }                                                                         \
    if (LASTWAIT) { asm volatile("s_waitcnt vmcnt(0)" ::: "memory"); }        \
    else          { asm volatile("s_waitcnt vmcnt(4)" ::: "memory"); }        \
    __builtin_amdgcn_sched_barrier(0);                                        \
    _Pragma("unroll") for (int _mt = 0; _mt < 4; ++_mt)                       \
        _Pragma("unroll") for (int _nt = 0; _nt < 4; ++_nt)                   \
            acc[_mt][_nt] = __builtin_amdgcn_mfma_f32_16x16x32_bf16(          \
                SET[_mt], bfr[_nt], acc[_mt][_nt], 0, 0, 0);                  \
    if (!(SKIP)) {                                                            \
      _Pragma("unroll") for (int _mt = 0; _mt < 4; ++_mt) {                   \
        ALOAD(SET[_mt], voff[_mt]);                                           \
        voff[_mt] += 1024;                                                    \
      }                                                                       \
    }                                                                         \
  }

// one kh-phase: 6 rolled double-steps (even step -> aregP, odd -> aregQ).
// LASTP: phase 2 (guard the tail prefetches + final drain).
#define COMPUTE_PH(P, BUF, LASTP)                                             \
  _Pragma("clang loop unroll(disable)") for (int _dd = 0; _dd < 6; ++_dd) {   \
    HALF_STEP(aregP, 2 * _dd, BUF, false, (LASTP) && _dd == 5)                \
    HALF_STEP(aregQ, 2 * _dd + 1, BUF, (LASTP) && _dd == 5,                   \
              (LASTP) && _dd == 5)                                            \
  }

// ---------- main implicit-GEMM MFMA kernel ----------
// 256 thr = 4 waves, each wave M64 x N64 (acc 4x4). Tile M256 x N64, grid 784.
// LDS: two kh-phase buffers, 68 rows x 256B each = 34816 B. 3 blocks/CU.
// A offsets are LINEAR in step s: voff = (wm*4+mt)*36864 + lane*16 + s*1024.
__global__ __launch_bounds__(256, 3)
void conv_gemm_kernel(const __hip_bfloat16* __restrict__ xp,
                      const __hip_bfloat16* __restrict__ wt,
                      const float* __restrict__ bias,
                      float* __restrict__ out) {
  __shared__ __align__(16) char smem[2][17408];

  const int tid = threadIdx.x;
  const int lane = tid & 63;
  const int wave = tid >> 6;
  const int col = lane & 15;
  const int quad = lane >> 4;

  // XCD-contiguous tiles: 784 = 8 XCD x 98 n-tiles (bijective: 784 % 8 == 0)
  const int id = blockIdx.x;
  const int xcd = id & 7;
  const int nt_ = xcd * 98 + (id >> 3);
  const int n0 = nt_ * 64;  // 64 consecutive pixels; never crosses an image

  // patch base: padded-pixel index of pixel n0 at tap (0,0)
  const int nimg0 = n0 / 3136;
  const int rem0 = n0 - nimg0 * 3136;
  const int hh0 = rem0 / 56;
  const int ww0 = rem0 - hh0 * 56;
  const int P0 = (nimg0 * 58 + hh0) * 58 + ww0;
  const char* pbase = (const char*)xp + (size_t)P0 * 256;

  STAGE(0, smem[0]);  // phase-0 patch in flight

  const uint64_t wtb64 = (uint64_t)(uintptr_t)wt;

  // voff[mt] = offset of the NEXT A-frag to issue for sub-panel mt
  uint32_t voff[4];
#pragma unroll
  for (int mt = 0; mt < 4; ++mt)
    voff[mt] = (uint32_t)((wave * 4 + mt) * 36864 + lane * 16);

  short8 aregP[4], aregQ[4], bfr[4];

  // prologue: issue A(0) -> P, A(1) -> Q (they drain at the barrier below)
#pragma unroll
  for (int mt = 0; mt < 4; ++mt) { ALOAD(aregP[mt], voff[mt]); voff[mt] += 1024; }
#pragma unroll
  for (int mt = 0; mt < 4; ++mt) { ALOAD(aregQ[mt], voff[mt]); voff[mt] += 1024; }

  // ---- per-lane patch row bases (tap (0,0)); tiles never cross images ----
  int rbase[4];
#pragma unroll
  for (int nt = 0; nt < 4; ++nt) {
    const int pix = n0 + nt * 16 + col;
    const int ni = pix / 3136;
    const int re = pix - ni * 3136;
    const int ph = re / 56;
    const int pw = re - ph * 56;
    rbase[nt] = (ni * 58 + ph) * 58 + pw - P0;
  }

  floatx4 acc[4][4];
#pragma unroll
  for (int a = 0; a < 4; ++a)
#pragma unroll
    for (int c = 0; c < 4; ++c) acc[a][c] = (floatx4)0.f;

  __syncthreads();      // phase-0 patch + A(0)/A(1) ready (barrier drains)
  STAGE(1, smem[1]);    // async: phase-1 staged during phase-0 compute
  COMPUTE_PH(0, smem[0], false);
  __syncthreads();      // phase-1 ready; all waves done reading buf0
  STAGE(2, smem[0]);    // async: phase-2 staged during phase-1 compute
  COMPUTE_PH(1, smem[1], false);
  __syncthreads();      // phase-2 ready
  COMPUTE_PH(2, smem[0], true);

  // ---- epilogue: bias + store (C/D: row m=quad*4+rr, col n=lane&15) ----
  const int rb = quad * 4;
#pragma unroll
  for (int nt = 0; nt < 4; ++nt) {
    const int pix = n0 + nt * 16 + col;
    const int nimg = pix / 3136;
    const int rem = pix - nimg * 3136;
    float* op = out + (size_t)nimg * (256 * 3136) + rem;
#pragma unroll
    for (int mt = 0; mt < 4; ++mt) {
      const int mb = wave * 64 + mt * 16 + rb;
#pragma unroll
      for (int rr = 0; rr < 4; ++rr) {
        op[(size_t)(mb + rr) * 3136] = acc[mt][nt][rr] + bias[mb + rr];
      }
    }
  }
}

// ---------- fallback: direct fp32 conv (only if ws too small) ----------
__global__ __launch_bounds__(256)
void direct_conv_kernel(const float* __restrict__ x, const float* __restrict__ wgt,
                        const float* __restrict__ bias, float* __restrict__ out) {
  const long t = (long)blockIdx.x * 256 + threadIdx.x;
  if (t >= 16L * 256 * 3136) return;
  const int w = t % 56;
  const int h = (t / 56) % 56;
  const int o = (t / 3136) % 256;
  const int n = t / (256L * 3136);
  float s = bias[o];
  for (int c = 0; c < 128; ++c)
    for (int kh = 0; kh < 3; ++kh) {
      const int hh = h + kh - 1;
      if (hh < 0 || hh >= 56) continue;
      for (int kw = 0; kw < 3; ++kw) {
        const int ww = w + kw - 1;
        if (ww < 0 || ww >= 56) continue;
        s += x[((size_t)(n * 128 + c) * 56 + hh) * 56 + ww] *
             wgt[((size_t)(o * 128 + c) * 3 + kh) * 3 + kw];
      }
    }
  out[t] = s;
}

extern "C" void kernel_launch(void* const* d_in, const int* in_sizes, int n_in,
                              void* d_out, int out_size, void* d_ws, size_t ws_size,
                              hipStream_t stream) {
  const float* x = (const float*)d_in[0];
  const float* w = (const float*)d_in[1];
  const float* b = (const float*)d_in[2];
  float* out = (float*)d_out;

  const size_t xp_bytes = (size_t)16 * 58 * 58 * 128 * 2;  // 13,778,944
  const size_t wt_bytes = (size_t)256 * 9 * 128 * 2;       //    589,824
  // Staging bounds: worst tile P0=53640, phase-2 last byte = (P0 + 2*58 + 68)
  // * 256 = 13,778,944 = exactly xp end. A-prefetch guarded (no read past wt).

  if (ws_size >= xp_bytes + wt_bytes) {
    __hip_bfloat16* xp = (__hip_bfloat16*)d_ws;
    __hip_bfloat16* wt = (__hip_bfloat16*)((char*)d_ws + xp_bytes);
    hipLaunchKernelGGL(pre_kernel, dim3(16 * 58 + 36), dim3(256), 0, stream,
                       x, w, xp, wt);
    hipLaunchKernelGGL(conv_gemm_kernel, dim3(784), dim3(256), 0, stream,
                       xp, wt, b, out);
  } else {
    const long total = 16L * 256 * 3136;
    hipLaunchKernelGGL(direct_conv_kernel, dim3((unsigned)((total + 255) / 256)),
                       dim3(256), 0, stream, x, w, b, out);
  }
}